// Round 4
// baseline (678.265 us; speedup 1.0000x reference)
//
#include <hip/hip_runtime.h>

#define NN 100000
#define NE 1600000
#define F  32
#define TWO_N (2 * NN)
#define SCAN_BLOCKS 196   // ceil(200000 / 1024)

// ---- init: cnt = 0, gsum = 0 (idempotent every call) ----
__global__ void k_init(int* __restrict__ cnt, float* __restrict__ gsum) {
    int i = blockIdx.x * blockDim.x + threadIdx.x;
    if (i < TWO_N) cnt[i] = 0;
    if (i == 0) gsum[0] = 0.f;
}

// ---- degree counts: cnt[0:N)=out-degree by src, cnt[N:2N)=in-degree by dst ----
__global__ void k_count(const int* __restrict__ src, const int* __restrict__ dst,
                        int* __restrict__ cnt) {
    int e = blockIdx.x * blockDim.x + threadIdx.x;
    if (e >= NE) return;
    atomicAdd(&cnt[src[e]], 1);
    atomicAdd(&cnt[NN + dst[e]], 1);
}

// ---- scan stage 1: per-block (1024 elems) exclusive scan + block sums ----
__global__ __launch_bounds__(256) void k_scanb(const int* __restrict__ cnt,
                                               int* __restrict__ off,
                                               int* __restrict__ bsum) {
    __shared__ int s[256];
    int t = threadIdx.x, b = blockIdx.x;
    int base = b * 1024 + t * 4;
    int v0 = (base + 0 < TWO_N) ? cnt[base + 0] : 0;
    int v1 = (base + 1 < TWO_N) ? cnt[base + 1] : 0;
    int v2 = (base + 2 < TWO_N) ? cnt[base + 2] : 0;
    int v3 = (base + 3 < TWO_N) ? cnt[base + 3] : 0;
    int lsum = v0 + v1 + v2 + v3;
    s[t] = lsum;
    __syncthreads();
    for (int d = 1; d < 256; d <<= 1) {
        int add = (t >= d) ? s[t - d] : 0;
        __syncthreads();
        s[t] += add;
        __syncthreads();
    }
    int excl = s[t] - lsum;  // exclusive prefix of this thread's chunk within block
    if (base + 0 < TWO_N) off[base + 0] = excl;            excl += v0;
    if (base + 1 < TWO_N) off[base + 1] = excl;            excl += v1;
    if (base + 2 < TWO_N) off[base + 2] = excl;            excl += v2;
    if (base + 3 < TWO_N) off[base + 3] = excl;
    if (t == 255) bsum[b] = s[255];
}

// ---- scan stage 2: exclusive scan of block sums (single block) ----
__global__ __launch_bounds__(256) void k_scant(const int* __restrict__ bsum,
                                               int* __restrict__ bbase) {
    __shared__ int s[256];
    int t = threadIdx.x;
    int v = (t < SCAN_BLOCKS) ? bsum[t] : 0;
    s[t] = v;
    __syncthreads();
    for (int d = 1; d < 256; d <<= 1) {
        int add = (t >= d) ? s[t - d] : 0;
        __syncthreads();
        s[t] += add;
        __syncthreads();
    }
    bbase[t] = s[t] - v;
}

// ---- scan stage 3: add block bases; init cursors; cap off[2N] ----
__global__ void k_scana(int* __restrict__ off, const int* __restrict__ bbase,
                        int* __restrict__ ocur) {
    int i = blockIdx.x * blockDim.x + threadIdx.x;
    if (i < TWO_N) {
        int v = off[i] + bbase[i >> 10];
        off[i] = v;
        ocur[i] = v;
    }
    if (i == 0) off[TWO_N] = 2 * NE;
}

// ---- fill CSR pools: out-lists then in-lists share one pool of 2E entries ----
__global__ void k_fill(const int* __restrict__ src, const int* __restrict__ dst,
                       const float* __restrict__ ew,
                       int* __restrict__ ocur,
                       int* __restrict__ nbr, float* __restrict__ wgt) {
    int e = blockIdx.x * blockDim.x + threadIdx.x;
    if (e >= NE) return;
    int s = src[e], d = dst[e];
    float w = ew[e];
    int po = atomicAdd(&ocur[s], 1);
    nbr[po] = d; wgt[po] = w;
    int pi = atomicAdd(&ocur[NN + d], 1);
    nbr[pi] = s; wgt[pi] = w;
}

// ---- gather: half-wave (32 lanes = 32 features) per node, independent loads ----
// To[i] = (1/deg_o) sum_out w*x[nbr] ; Ti[i] = (1/deg_i) sum_in w*x[nbr]
__global__ __launch_bounds__(256) void k_gather(const float* __restrict__ x,
                                                const int* __restrict__ off,
                                                const int* __restrict__ nbr,
                                                const float* __restrict__ wgt,
                                                float* __restrict__ To,
                                                float* __restrict__ Ti) {
    int tid = threadIdx.x;
    int f = tid & 31;
    int i = blockIdx.x * 8 + (tid >> 5);
    if (i >= NN) return;
    int o0 = off[i], o1 = off[i + 1];
    int i0 = off[NN + i], i1 = off[NN + i + 1];

    float acc = 0.f, deg = 0.f;
    for (int j = o0; j < o1; j++) {
        int n = nbr[j];
        float w = wgt[j];
        deg += w;
        acc += w * x[(size_t)n * F + f];
    }
    To[(size_t)i * F + f] = acc / deg;

    acc = 0.f; deg = 0.f;
    for (int j = i0; j < i1; j++) {
        int n = nbr[j];
        float w = wgt[j];
        deg += w;
        acc += w * x[(size_t)n * F + f];
    }
    Ti[(size_t)i * F + f] = acc / deg;
}

// ---- gates: thread per node, weights broadcast from LDS (verified round-3 math) ----
// gz = x@(Wz00+Wz10) + To@Wz01 + Ti@Wz11 + bz ; gh likewise with Wh.
// H = (1-sigmoid(gz))*tanh(gh); s = relu(H).Wlin summed into gsum.
__global__ __launch_bounds__(256) void RecurrentGCN_69587060130083_kernel(
    const float* __restrict__ x,
    const float* __restrict__ To, const float* __restrict__ Ti,
    const float* __restrict__ Wz, const float* __restrict__ bz,
    const float* __restrict__ Wh, const float* __restrict__ bh,
    const float* __restrict__ Wl,
    float* __restrict__ gsum)
{
    __shared__ float sWz0[1024], sWzo[1024], sWzi[1024];
    __shared__ float sWh0[1024], sWho[1024], sWhi[1024];
    __shared__ float sbz[32], sbh[32], swl[32];
    __shared__ float wsum[4];
    int tid = threadIdx.x;

    for (int idx = tid; idx < 1024; idx += 256) {
        int c = idx >> 5, f = idx & 31;
        int tr = f * 32 + c;
        // W[dir,k,c,f] flat = dir*4096 + k*2048 + c*32 + f ; only c<32 matters (H=0)
        sWz0[tr] = Wz[idx] + Wz[4096 + idx];
        sWzo[tr] = Wz[2048 + idx];
        sWzi[tr] = Wz[6144 + idx];
        sWh0[tr] = Wh[idx] + Wh[4096 + idx];
        sWho[tr] = Wh[2048 + idx];
        sWhi[tr] = Wh[6144 + idx];
    }
    if (tid < 32) {
        sbz[tid] = bz[tid];
        sbh[tid] = bh[tid];
        swl[tid] = Wl[tid];
    }
    __syncthreads();

    int i = blockIdx.x * 256 + tid;
    float s_acc = 0.f;
    if (i < NN) {
        float xv[F], tov[F], tiv[F];
        const float4* xr = (const float4*)(x + (size_t)i * F);
        const float4* tor = (const float4*)(To + (size_t)i * F);
        const float4* tir = (const float4*)(Ti + (size_t)i * F);
#pragma unroll
        for (int j = 0; j < 8; j++) {
            float4 p = xr[j];
            xv[4*j+0] = p.x; xv[4*j+1] = p.y; xv[4*j+2] = p.z; xv[4*j+3] = p.w;
            float4 a = tor[j];
            tov[4*j+0] = a.x; tov[4*j+1] = a.y; tov[4*j+2] = a.z; tov[4*j+3] = a.w;
            float4 b = tir[j];
            tiv[4*j+0] = b.x; tiv[4*j+1] = b.y; tiv[4*j+2] = b.z; tiv[4*j+3] = b.w;
        }
#pragma unroll 4
        for (int f = 0; f < 32; f++) {
            float gz = sbz[f], gh = sbh[f];
            const float* wz0 = &sWz0[f * 32];
            const float* wzo = &sWzo[f * 32];
            const float* wzi = &sWzi[f * 32];
            const float* wh0 = &sWh0[f * 32];
            const float* who = &sWho[f * 32];
            const float* whi = &sWhi[f * 32];
#pragma unroll
            for (int c = 0; c < 32; c++) {
                gz += xv[c] * wz0[c] + tov[c] * wzo[c] + tiv[c] * wzi[c];
                gh += xv[c] * wh0[c] + tov[c] * who[c] + tiv[c] * whi[c];
            }
            float Z  = 1.f / (1.f + __expf(-gz));
            float Ht = tanhf(gh);
            float hv = (1.f - Z) * Ht;
            hv = hv > 0.f ? hv : 0.f;
            s_acc += hv * swl[f];
        }
    }
#pragma unroll
    for (int off = 32; off > 0; off >>= 1) s_acc += __shfl_down(s_acc, off);
    if ((tid & 63) == 0) wsum[tid >> 6] = s_acc;
    __syncthreads();
    if (tid == 0) atomicAdd(gsum, wsum[0] + wsum[1] + wsum[2] + wsum[3]);
}

__global__ void k_final(const float* __restrict__ gsum,
                        const float* __restrict__ blin,
                        float* __restrict__ out) {
    out[0] = gsum[0] / (float)NN + blin[0];
}

extern "C" void kernel_launch(void* const* d_in, const int* in_sizes, int n_in,
                              void* d_out, int out_size, void* d_ws, size_t ws_size,
                              hipStream_t stream) {
    const float* x  = (const float*)d_in[0];
    const float* ew = (const float*)d_in[1];
    const float* Wz = (const float*)d_in[2];
    const float* bz = (const float*)d_in[3];
    // d_in[4], d_in[5] = W_r, b_r: dead (H=0 => H*R=0)
    const float* Wh = (const float*)d_in[6];
    const float* bh = (const float*)d_in[7];
    const float* Wl = (const float*)d_in[8];
    const float* bl = (const float*)d_in[9];
    const int* ei  = (const int*)d_in[10];
    const int* src = ei;
    const int* dst = ei + NE;

    // ws layout (4B words):
    // cnt[2N] | off[2N+1] | ocur[2N] | bsum[256] | bbase[256] |
    // nbr[2E] | wgt[2E] | To[32N] | Ti[32N] | gsum   (~53.6 MB)
    int* iws   = (int*)d_ws;
    int* cnt   = iws;
    int* off   = cnt + TWO_N;
    int* ocur  = off + TWO_N + 1;
    int* bsum  = ocur + TWO_N;
    int* bbase = bsum + 256;
    int* nbr   = bbase + 256;
    float* wgt = (float*)(nbr + 2 * NE);
    float* To  = wgt + 2 * NE;
    float* Ti  = To + (size_t)NN * F;
    float* gsum = Ti + (size_t)NN * F;

    k_init <<<(TWO_N + 255) / 256, 256, 0, stream>>>(cnt, gsum);
    k_count<<<(NE + 255) / 256, 256, 0, stream>>>(src, dst, cnt);
    k_scanb<<<SCAN_BLOCKS, 256, 0, stream>>>(cnt, off, bsum);
    k_scant<<<1, 256, 0, stream>>>(bsum, bbase);
    k_scana<<<(TWO_N + 255) / 256, 256, 0, stream>>>(off, bbase, ocur);
    k_fill <<<(NE + 255) / 256, 256, 0, stream>>>(src, dst, ew, ocur, nbr, wgt);
    k_gather<<<(NN + 7) / 8, 256, 0, stream>>>(x, off, nbr, wgt, To, Ti);
    RecurrentGCN_69587060130083_kernel<<<(NN + 255) / 256, 256, 0, stream>>>(
        x, To, Ti, Wz, bz, Wh, bh, Wl, gsum);
    k_final<<<1, 1, 0, stream>>>(gsum, bl, (float*)d_out);
}

// Round 5
// 612.763 us; speedup vs baseline: 1.1069x; 1.1069x over previous
//
#include <hip/hip_runtime.h>

#define NN 100000
#define NE 1600000
#define F  32
#define TWO_N (2 * NN)
#define SCAN_BLOCKS 196   // ceil(200000 / 1024)
#define PS 2              // cursor pad stride (ints): 8 cursors/line instead of 16
#define PART_N 12500      // nodes per XCD partition (NN/8)
#define PART_GRID 2048    // 8 partitions x 256 block-groups

// ---- init: padded count/cursor array = 0, gsum = 0 (idempotent every call) ----
__global__ void k_init(int* __restrict__ cur, float* __restrict__ gsum) {
    int i = blockIdx.x * blockDim.x + threadIdx.x;
    if (i < TWO_N * PS) cur[i] = 0;
    if (i == 0) gsum[0] = 0.f;
}

// ---- degree counts, XCD-partitioned: partition r handles nodes [r*PART_N, ...) ----
// blockIdx%8 -> XCD round-robin, so each cursor line is atomically updated by ONE XCD.
__global__ __launch_bounds__(256) void k_count(const int* __restrict__ src,
                                               const int* __restrict__ dst,
                                               int* __restrict__ cur) {
    int part = blockIdx.x & 7;
    int grp  = blockIdx.x >> 3;
    int ngrp = gridDim.x >> 3;
    int lo = part * PART_N, hi = lo + PART_N;
    for (int e = grp * 256 + threadIdx.x; e < NE; e += ngrp * 256) {
        int s = src[e], d = dst[e];
        if (s >= lo && s < hi) atomicAdd(&cur[(size_t)s * PS], 1);
        if (d >= lo && d < hi) atomicAdd(&cur[(size_t)(NN + d) * PS], 1);
    }
}

// ---- scan stage 1: per-block (1024 elems) exclusive scan + block sums ----
__global__ __launch_bounds__(256) void k_scanb(const int* __restrict__ cur,
                                               int* __restrict__ off,
                                               int* __restrict__ bsum) {
    __shared__ int s[256];
    int t = threadIdx.x, b = blockIdx.x;
    int base = b * 1024 + t * 4;
    int v0 = (base + 0 < TWO_N) ? cur[(size_t)(base + 0) * PS] : 0;
    int v1 = (base + 1 < TWO_N) ? cur[(size_t)(base + 1) * PS] : 0;
    int v2 = (base + 2 < TWO_N) ? cur[(size_t)(base + 2) * PS] : 0;
    int v3 = (base + 3 < TWO_N) ? cur[(size_t)(base + 3) * PS] : 0;
    int lsum = v0 + v1 + v2 + v3;
    s[t] = lsum;
    __syncthreads();
    for (int d = 1; d < 256; d <<= 1) {
        int add = (t >= d) ? s[t - d] : 0;
        __syncthreads();
        s[t] += add;
        __syncthreads();
    }
    int excl = s[t] - lsum;
    if (base + 0 < TWO_N) off[base + 0] = excl;            excl += v0;
    if (base + 1 < TWO_N) off[base + 1] = excl;            excl += v1;
    if (base + 2 < TWO_N) off[base + 2] = excl;            excl += v2;
    if (base + 3 < TWO_N) off[base + 3] = excl;
    if (t == 255) bsum[b] = s[255];
}

// ---- scan stage 2: exclusive scan of block sums (single block) ----
__global__ __launch_bounds__(256) void k_scant(const int* __restrict__ bsum,
                                               int* __restrict__ bbase) {
    __shared__ int s[256];
    int t = threadIdx.x;
    int v = (t < SCAN_BLOCKS) ? bsum[t] : 0;
    s[t] = v;
    __syncthreads();
    for (int d = 1; d < 256; d <<= 1) {
        int add = (t >= d) ? s[t - d] : 0;
        __syncthreads();
        s[t] += add;
        __syncthreads();
    }
    bbase[t] = s[t] - v;
}

// ---- scan stage 3: off = global exclusive prefix; cursor array <- starts ----
__global__ void k_scana(int* __restrict__ off, const int* __restrict__ bbase,
                        int* __restrict__ cur) {
    int i = blockIdx.x * blockDim.x + threadIdx.x;
    if (i < TWO_N) {
        int v = off[i] + bbase[i >> 10];
        off[i] = v;
        cur[(size_t)i * PS] = v;   // counts already consumed by scanb
    }
    if (i == 0) off[TWO_N] = 2 * NE;
}

// ---- fill CSR pool, XCD-partitioned; (nbr,wgt) packed as int2 single store ----
// Pool lines for partition r's nodes are written only from XCD r -> no L2 ping-pong.
__global__ __launch_bounds__(256) void k_fill(const int* __restrict__ src,
                                              const int* __restrict__ dst,
                                              const float* __restrict__ ew,
                                              int* __restrict__ cur,
                                              int2* __restrict__ pool) {
    int part = blockIdx.x & 7;
    int grp  = blockIdx.x >> 3;
    int ngrp = gridDim.x >> 3;
    int lo = part * PART_N, hi = lo + PART_N;
    for (int e = grp * 256 + threadIdx.x; e < NE; e += ngrp * 256) {
        int s = src[e], d = dst[e];
        bool ws_ = (s >= lo && s < hi);
        bool wd_ = (d >= lo && d < hi);
        if (ws_ || wd_) {
            float w = ew[e];
            if (ws_) {
                int p = atomicAdd(&cur[(size_t)s * PS], 1);
                pool[p] = make_int2(d, __float_as_int(w));
            }
            if (wd_) {
                int p = atomicAdd(&cur[(size_t)(NN + d) * PS], 1);
                pool[p] = make_int2(s, __float_as_int(w));
            }
        }
    }
}

// ---- gather: half-wave (32 lanes = 32 features) per node, independent loads ----
__global__ __launch_bounds__(256) void k_gather(const float* __restrict__ x,
                                                const int* __restrict__ off,
                                                const int2* __restrict__ pool,
                                                float* __restrict__ To,
                                                float* __restrict__ Ti) {
    int tid = threadIdx.x;
    int f = tid & 31;
    int i = blockIdx.x * 8 + (tid >> 5);
    if (i >= NN) return;
    int o0 = off[i], o1 = off[i + 1];
    int i0 = off[NN + i], i1 = off[NN + i + 1];

    float acc = 0.f, deg = 0.f;
    for (int j = o0; j < o1; j++) {
        int2 p = pool[j];
        float w = __int_as_float(p.y);
        deg += w;
        acc += w * x[(size_t)p.x * F + f];
    }
    To[(size_t)i * F + f] = acc / deg;

    acc = 0.f; deg = 0.f;
    for (int j = i0; j < i1; j++) {
        int2 p = pool[j];
        float w = __int_as_float(p.y);
        deg += w;
        acc += w * x[(size_t)p.x * F + f];
    }
    Ti[(size_t)i * F + f] = acc / deg;
}

// ---- gates: thread per node, weights broadcast from LDS (verified math) ----
// gz = x@(Wz00+Wz10) + To@Wz01 + Ti@Wz11 + bz ; gh likewise with Wh.
// H = (1-sigmoid(gz))*tanh(gh); s = relu(H).Wlin summed into gsum.
__global__ __launch_bounds__(256) void RecurrentGCN_69587060130083_kernel(
    const float* __restrict__ x,
    const float* __restrict__ To, const float* __restrict__ Ti,
    const float* __restrict__ Wz, const float* __restrict__ bz,
    const float* __restrict__ Wh, const float* __restrict__ bh,
    const float* __restrict__ Wl,
    float* __restrict__ gsum)
{
    __shared__ float sWz0[1024], sWzo[1024], sWzi[1024];
    __shared__ float sWh0[1024], sWho[1024], sWhi[1024];
    __shared__ float sbz[32], sbh[32], swl[32];
    __shared__ float wsum[4];
    int tid = threadIdx.x;

    for (int idx = tid; idx < 1024; idx += 256) {
        int c = idx >> 5, f = idx & 31;
        int tr = f * 32 + c;
        // W[dir,k,c,f] flat = dir*4096 + k*2048 + c*32 + f ; only c<32 matters (H=0)
        sWz0[tr] = Wz[idx] + Wz[4096 + idx];
        sWzo[tr] = Wz[2048 + idx];
        sWzi[tr] = Wz[6144 + idx];
        sWh0[tr] = Wh[idx] + Wh[4096 + idx];
        sWho[tr] = Wh[2048 + idx];
        sWhi[tr] = Wh[6144 + idx];
    }
    if (tid < 32) {
        sbz[tid] = bz[tid];
        sbh[tid] = bh[tid];
        swl[tid] = Wl[tid];
    }
    __syncthreads();

    int i = blockIdx.x * 256 + tid;
    float s_acc = 0.f;
    if (i < NN) {
        float xv[F], tov[F], tiv[F];
        const float4* xr = (const float4*)(x + (size_t)i * F);
        const float4* tor = (const float4*)(To + (size_t)i * F);
        const float4* tir = (const float4*)(Ti + (size_t)i * F);
#pragma unroll
        for (int j = 0; j < 8; j++) {
            float4 p = xr[j];
            xv[4*j+0] = p.x; xv[4*j+1] = p.y; xv[4*j+2] = p.z; xv[4*j+3] = p.w;
            float4 a = tor[j];
            tov[4*j+0] = a.x; tov[4*j+1] = a.y; tov[4*j+2] = a.z; tov[4*j+3] = a.w;
            float4 b = tir[j];
            tiv[4*j+0] = b.x; tiv[4*j+1] = b.y; tiv[4*j+2] = b.z; tiv[4*j+3] = b.w;
        }
#pragma unroll 4
        for (int f = 0; f < 32; f++) {
            float gz = sbz[f], gh = sbh[f];
            const float* wz0 = &sWz0[f * 32];
            const float* wzo = &sWzo[f * 32];
            const float* wzi = &sWzi[f * 32];
            const float* wh0 = &sWh0[f * 32];
            const float* who = &sWho[f * 32];
            const float* whi = &sWhi[f * 32];
#pragma unroll
            for (int c = 0; c < 32; c++) {
                gz += xv[c] * wz0[c] + tov[c] * wzo[c] + tiv[c] * wzi[c];
                gh += xv[c] * wh0[c] + tov[c] * who[c] + tiv[c] * whi[c];
            }
            float Z  = 1.f / (1.f + __expf(-gz));
            float Ht = tanhf(gh);
            float hv = (1.f - Z) * Ht;
            hv = hv > 0.f ? hv : 0.f;
            s_acc += hv * swl[f];
        }
    }
#pragma unroll
    for (int off = 32; off > 0; off >>= 1) s_acc += __shfl_down(s_acc, off);
    if ((tid & 63) == 0) wsum[tid >> 6] = s_acc;
    __syncthreads();
    if (tid == 0) atomicAdd(gsum, wsum[0] + wsum[1] + wsum[2] + wsum[3]);
}

__global__ void k_final(const float* __restrict__ gsum,
                        const float* __restrict__ blin,
                        float* __restrict__ out) {
    out[0] = gsum[0] / (float)NN + blin[0];
}

extern "C" void kernel_launch(void* const* d_in, const int* in_sizes, int n_in,
                              void* d_out, int out_size, void* d_ws, size_t ws_size,
                              hipStream_t stream) {
    const float* x  = (const float*)d_in[0];
    const float* ew = (const float*)d_in[1];
    const float* Wz = (const float*)d_in[2];
    const float* bz = (const float*)d_in[3];
    // d_in[4], d_in[5] = W_r, b_r: dead (H=0 => H*R=0)
    const float* Wh = (const float*)d_in[6];
    const float* bh = (const float*)d_in[7];
    const float* Wl = (const float*)d_in[8];
    const float* bl = (const float*)d_in[9];
    const int* ei  = (const int*)d_in[10];
    const int* src = ei;
    const int* dst = ei + NE;

    // ws layout (4B words), total 53.6 MB (same as proven round-4 footprint):
    // cur[2N*PS] (counts then cursors) | off[2N+1] | bsum[256] | bbase[256] |
    // pool[2E int2] | To[32N] | Ti[32N] | gsum
    int* iws   = (int*)d_ws;
    int* cur   = iws;
    int* off   = cur + (size_t)TWO_N * PS;
    int* bsum  = off + TWO_N + 1;
    int* bbase = bsum + 256;
    int2* pool = (int2*)(bbase + 256);
    float* To  = (float*)(pool + 2 * NE);
    float* Ti  = To + (size_t)NN * F;
    float* gsum = Ti + (size_t)NN * F;

    k_init <<<(TWO_N * PS + 255) / 256, 256, 0, stream>>>(cur, gsum);
    k_count<<<PART_GRID, 256, 0, stream>>>(src, dst, cur);
    k_scanb<<<SCAN_BLOCKS, 256, 0, stream>>>(cur, off, bsum);
    k_scant<<<1, 256, 0, stream>>>(bsum, bbase);
    k_scana<<<(TWO_N + 255) / 256, 256, 0, stream>>>(off, bbase, cur);
    k_fill <<<PART_GRID, 256, 0, stream>>>(src, dst, ew, cur, pool);
    k_gather<<<(NN + 7) / 8, 256, 0, stream>>>(x, off, pool, To, Ti);
    RecurrentGCN_69587060130083_kernel<<<(NN + 255) / 256, 256, 0, stream>>>(
        x, To, Ti, Wz, bz, Wh, bh, Wl, gsum);
    k_final<<<1, 1, 0, stream>>>(gsum, bl, (float*)d_out);
}